// Round 3
// baseline (109.438 us; speedup 1.0000x reference)
//
#include <hip/hip_runtime.h>
#include <math.h>

#define NB   2
#define CIN  128
#define CH   64
#define NPOS 4096
#define LOG2E 1.4426950408889634f

typedef __attribute__((ext_vector_type(8))) short s16x8;   // 8 bf16 (4 VGPRs)
typedef __attribute__((ext_vector_type(4))) float f32x4;

// frag-block global layouts (shorts):
//  kF/qF: FB(b, pos-tile16, kc) + lane*8 + elem   (1 KB per frag-block)
//  vF   : VB(b, c-tile16, i-tile32) + lane*8 + elem
// NOTE: kF stores k * log2(e)  (folded at projection time) so score MFMAs
// produce s*log2e and softmax exponentials are bare v_exp_f32 (exp2f).
#define FB(b,T,kc) ((((size_t)(b) * 256 + (size_t)(T)) * 2 + (size_t)(kc)) * 512)
#define VB(b,ct,it) ((((size_t)(b) * 4 + (size_t)(ct)) * 128 + (size_t)(it)) * 512)

__device__ __forceinline__ unsigned int bfrne(float f) {
    unsigned int u = __float_as_uint(f);
    return (u + 0x7FFFu + ((u >> 16) & 1u)) >> 16;
}
__device__ __forceinline__ unsigned int pk_rne(float lo, float hi) {
    return bfrne(lo) | (bfrne(hi) << 16);
}
// fast half-up pack for non-negative values (exp outputs)
__device__ __forceinline__ unsigned int pk_fast(float lo, float hi) {
    unsigned int a = (__float_as_uint(lo) + 0x8000u) >> 16;
    unsigned int b = (__float_as_uint(hi) + 0x8000u) & 0xFFFF0000u;
    return a | b;
}
__device__ __forceinline__ float bf2f(unsigned short h) {
    return __uint_as_float(((unsigned int)h) << 16);
}

// ---------------------------------------------------------------------------
// Kernel 1: q/k/v projections via MFMA, outputs in frag-block layouts.
// Round-3 change: Wk rows are scaled by log2(e) while packing (uniform
// per-tile multiplier; ~32 extra v_mul per tile, negligible).
// ---------------------------------------------------------------------------
#define XTS 132
__global__ __launch_bounds__(256) void qkv_kernel(
    const float* __restrict__ x,
    const float* __restrict__ Wq, const float* __restrict__ Wk,
    const float* __restrict__ Wv,
    unsigned short* __restrict__ kF, unsigned short* __restrict__ qF,
    unsigned short* __restrict__ vF)
{
    __shared__ __align__(16) float xT[16 * XTS];   // 8.25 KB
    const int b  = blockIdx.y;
    const int pt = blockIdx.x;                     // 16-pos tile index
    const int p0 = pt * 16;
    const int tid = threadIdx.x;

    #pragma unroll
    for (int it = 0; it < 2; ++it) {
        int idx = it * 256 + tid;                  // 0..511
        int c = idx >> 2, p4 = (idx & 3) * 4;
        float4 g = *(const float4*)&x[((size_t)b * CIN + c) * NPOS + p0 + p4];
        xT[(p4 + 0) * XTS + c] = g.x;
        xT[(p4 + 1) * XTS + c] = g.y;
        xT[(p4 + 2) * XTS + c] = g.z;
        xT[(p4 + 3) * XTS + c] = g.w;
    }
    __syncthreads();

    const int w = tid >> 6, l = tid & 63, lm = l & 15, lq = l >> 4;

    s16x8 Bhi[4], Blo[4];
    #pragma unroll
    for (int ck = 0; ck < 4; ++ck) {
        const float* xr = &xT[lm * XTS + ck * 32 + lq * 8];
        union { unsigned int u[4]; s16x8 v; } chv, clv;
        #pragma unroll
        for (int j = 0; j < 4; ++j) {
            float x0 = xr[2 * j], x1 = xr[2 * j + 1];
            unsigned int h0 = bfrne(x0), h1 = bfrne(x1);
            chv.u[j] = h0 | (h1 << 16);
            clv.u[j] = pk_rne(x0 - __uint_as_float(h0 << 16),
                              x1 - __uint_as_float(h1 << 16));
        }
        Bhi[ck] = chv.v; Blo[ck] = clv.v;
    }

    #pragma unroll
    for (int t3 = 0; t3 < 3; ++t3) {
        const int tile = w * 3 + t3;
        const int mat = tile >> 2, o0 = (tile & 3) * 16;
        const float* __restrict__ W = (mat == 0) ? Wq : (mat == 1) ? Wk : Wv;
        const float km = (mat == 1) ? LOG2E : 1.0f;   // fold log2e into k
        f32x4 acc = {0.f, 0.f, 0.f, 0.f};
        #pragma unroll
        for (int ck = 0; ck < 4; ++ck) {
            const float* wp = W + (o0 + lm) * CIN + ck * 32 + lq * 8;
            union { unsigned int u[4]; s16x8 v; } ca;
            #pragma unroll
            for (int j = 0; j < 4; ++j)
                ca.u[j] = pk_rne(wp[2*j] * km, wp[2*j+1] * km);
            acc = __builtin_amdgcn_mfma_f32_16x16x32_bf16(ca.v, Bhi[ck], acc, 0,0,0);
            acc = __builtin_amdgcn_mfma_f32_16x16x32_bf16(ca.v, Blo[ck], acc, 0,0,0);
        }
        // C-frag: value at (c = o0 + 4*lq + r, p = p0 + lm)
        if (mat < 2) {
            unsigned short* dst = (mat == 0) ? qF : kF;
            const int kc = o0 >> 5;
            const int lane2 = lm + 16 * (((o0 & 31) >> 3) + (lq >> 1));
            uint2 st = make_uint2(pk_rne(acc[0], acc[1]), pk_rne(acc[2], acc[3]));
            *(uint2*)&dst[FB(b, pt, kc) + lane2 * 8 + (lq & 1) * 4] = st;
        } else {
            const int ct = o0 >> 4;
            const int itile = pt >> 1;
            const int lanebase = 16 * ((pt & 1) * 2 + (lm >> 3));
            #pragma unroll
            for (int r = 0; r < 4; ++r)
                vF[VB(b, ct, itile) + (size_t)(4 * lq + r + lanebase) * 8
                   + (lm & 7)] = (unsigned short)bfrne(acc[r]);
        }
    }
}

// ---------------------------------------------------------------------------
// Kernel 2: softmax denominator partials over j-EIGHTHS.  Grid (32, 8, b)
// = 512 blocks.  Each WAVE independently owns one 32-i tile (it = bx*4+w)
// and sweeps its 512-j slice: NO LDS, NO barriers — every fragment is one
// coalesced b128 load from kF/qF.  Prefetch depth 2 (unroll-by-2 ping-pong).
// Round-3 change: scores arrive pre-scaled by log2e (kF fold), so the
// exponential is a bare v_exp_f32 via exp2f — removes 32 v_mul per iter
// from the dominant VALU chain.
// ---------------------------------------------------------------------------
__global__ __launch_bounds__(256, 4) void stats_kernel(
    const unsigned short* __restrict__ kF,
    const unsigned short* __restrict__ qF,
    float* __restrict__ lpart)
{
    const int b  = blockIdx.z;
    const int jq = blockIdx.y;
    const int tid = threadIdx.x;
    const int w = tid >> 6, l = tid & 63, lm = l & 15, lq = l >> 4;
    const int it = blockIdx.x * 4 + w;             // 32-i tile, 0..127

    s16x8 a[2][2];
    #pragma unroll
    for (int s = 0; s < 2; ++s)
        #pragma unroll
        for (int kc = 0; kc < 2; ++kc)
            a[s][kc] = *(const s16x8*)&kF[FB(b, it * 2 + s, kc) + l * 8];

    const unsigned short* q0 = qF + FB(b, jq * 32, 0);   // 32 j-tiles, 1 KB each kc
    s16x8 nb0[2], nb1[2];
    nb0[0] = *(const s16x8*)&q0[l * 8];
    nb0[1] = *(const s16x8*)&q0[512 + l * 8];
    nb1[0] = *(const s16x8*)&q0[1024 + l * 8];
    nb1[1] = *(const s16x8*)&q0[1024 + 512 + l * 8];

    float rs[2][4] = {};
    #pragma unroll 1
    for (int t = 0; t < 32; t += 2) {
        // sub-iter A: j-tile t (from nb0); prefetch t+2 into nb0
        {
            s16x8 b0 = nb0[0], b1 = nb0[1];
            if (t < 30) {
                nb0[0] = *(const s16x8*)&q0[(size_t)(t + 2) * 1024 + l * 8];
                nb0[1] = *(const s16x8*)&q0[(size_t)(t + 2) * 1024 + 512 + l * 8];
            }
            #pragma unroll
            for (int s = 0; s < 2; ++s) {
                f32x4 sc = {0.f, 0.f, 0.f, 0.f};
                sc = __builtin_amdgcn_mfma_f32_16x16x32_bf16(a[s][0], b0, sc, 0,0,0);
                sc = __builtin_amdgcn_mfma_f32_16x16x32_bf16(a[s][1], b1, sc, 0,0,0);
                rs[s][0] += exp2f(sc[0]); rs[s][1] += exp2f(sc[1]);
                rs[s][2] += exp2f(sc[2]); rs[s][3] += exp2f(sc[3]);
            }
        }
        // sub-iter B: j-tile t+1 (from nb1); prefetch t+3 into nb1
        {
            s16x8 b0 = nb1[0], b1 = nb1[1];
            if (t < 30) {
                nb1[0] = *(const s16x8*)&q0[(size_t)(t + 3) * 1024 + l * 8];
                nb1[1] = *(const s16x8*)&q0[(size_t)(t + 3) * 1024 + 512 + l * 8];
            }
            #pragma unroll
            for (int s = 0; s < 2; ++s) {
                f32x4 sc = {0.f, 0.f, 0.f, 0.f};
                sc = __builtin_amdgcn_mfma_f32_16x16x32_bf16(a[s][0], b0, sc, 0,0,0);
                sc = __builtin_amdgcn_mfma_f32_16x16x32_bf16(a[s][1], b1, sc, 0,0,0);
                rs[s][0] += exp2f(sc[0]); rs[s][1] += exp2f(sc[1]);
                rs[s][2] += exp2f(sc[2]); rs[s][3] += exp2f(sc[3]);
            }
        }
    }

    #pragma unroll
    for (int s = 0; s < 2; ++s)
        #pragma unroll
        for (int r = 0; r < 4; ++r) {
            rs[s][r] += __shfl_xor(rs[s][r], 1);
            rs[s][r] += __shfl_xor(rs[s][r], 2);
            rs[s][r] += __shfl_xor(rs[s][r], 4);
            rs[s][r] += __shfl_xor(rs[s][r], 8);
        }
    if (lm == 0) {
        #pragma unroll
        for (int s = 0; s < 2; ++s)
            #pragma unroll
            for (int r = 0; r < 4; ++r)
                lpart[(size_t)jq * NB * NPOS + b * NPOS
                      + it * 32 + s * 16 + lq * 4 + r] = rs[s][r];
    }
}

// ---------------------------------------------------------------------------
// Kernel 3: aggregation over i-EIGHTHS.  Grid (32, 8, b) = 512 blocks.
// rls stores -log2(l[i]); score-MFMA C-init = -log2(l) broadcast per i-row,
// so P = exp2(s*log2e - log2 l) = exp(s)/l — a bare v_exp_f32, zero muls.
// s_setprio(1) around MFMA clusters (barrier-free independent waves).
// ---------------------------------------------------------------------------
__global__ __launch_bounds__(256, 3) void agg_kernel(
    const unsigned short* __restrict__ kF,
    const unsigned short* __restrict__ qF,
    const unsigned short* __restrict__ vF,
    const float* __restrict__ lpart,
    unsigned short* __restrict__ U)
{
    __shared__ __align__(16) unsigned short wts[4][16][40];  // 5 KB
    __shared__ __align__(16) float rls[512];                 // 2 KB
    const int b  = blockIdx.z;
    const int iq = blockIdx.y;
    const int j0 = blockIdx.x * 128;
    const int tid = threadIdx.x;
    const int w = tid >> 6, l = tid & 63, lm = l & 15, lq = l >> 4;

    // inline gl: reduce 8 lpart partials for this block's 512-i slice,
    // store NEGATED LOG2 of the denominator
    {
        const float* lp = lpart + (size_t)b * NPOS + iq * 512 + tid * 2;
        float s0 = 0.f, s1 = 0.f;
        #pragma unroll
        for (int qq = 0; qq < 8; ++qq) {
            float2 lv = *(const float2*)(lp + (size_t)qq * NB * NPOS);
            s0 += lv.x; s1 += lv.y;
        }
        rls[tid * 2 + 0] = -__log2f(s0);
        rls[tid * 2 + 1] = -__log2f(s1);
    }

    s16x8 qb[2][2];
    #pragma unroll
    for (int js = 0; js < 2; ++js)
        #pragma unroll
        for (int kc = 0; kc < 2; ++kc)
            qb[js][kc] = *(const s16x8*)&qF[
                FB(b, blockIdx.x * 8 + w * 2 + js, kc) + l * 8];

    f32x4 acc[2][4] = {};
    s16x8 nk[2][2], nv[4];
    #pragma unroll
    for (int s = 0; s < 2; ++s)
        #pragma unroll
        for (int kc = 0; kc < 2; ++kc)
            nk[s][kc] = *(const s16x8*)&kF[FB(b, iq * 32 + s, kc) + l * 8];
    #pragma unroll
    for (int cs = 0; cs < 4; ++cs)
        nv[cs] = *(const s16x8*)&vF[VB(b, cs, iq * 16) + l * 8];

    __syncthreads();   // rls ready (only barrier)

    for (int t = 0; t < 16; ++t) {
        s16x8 kA[2][2] = {{nk[0][0], nk[0][1]}, {nk[1][0], nk[1][1]}};
        s16x8 vA[4] = {nv[0], nv[1], nv[2], nv[3]};
        if (t < 15) {
            #pragma unroll
            for (int s = 0; s < 2; ++s)
                #pragma unroll
                for (int kc = 0; kc < 2; ++kc)
                    nk[s][kc] = *(const s16x8*)&kF[
                        FB(b, iq * 32 + (t + 1) * 2 + s, kc) + l * 8];
            #pragma unroll
            for (int cs = 0; cs < 4; ++cs)
                nv[cs] = *(const s16x8*)&vF[VB(b, cs, iq * 16 + t + 1) + l * 8];
        }

        f32x4 nl0 = *(const f32x4*)&rls[t * 32 + lq * 4];
        f32x4 nl1 = *(const f32x4*)&rls[t * 32 + 16 + lq * 4];

        #pragma unroll
        for (int js = 0; js < 2; ++js) {
            f32x4 s0 = nl0, s1 = nl1;   // C-init = -log2(l[i]) per i-row
            __builtin_amdgcn_s_setprio(1);
            s0 = __builtin_amdgcn_mfma_f32_16x16x32_bf16(kA[0][0], qb[js][0], s0, 0,0,0);
            s0 = __builtin_amdgcn_mfma_f32_16x16x32_bf16(kA[0][1], qb[js][1], s0, 0,0,0);
            s1 = __builtin_amdgcn_mfma_f32_16x16x32_bf16(kA[1][0], qb[js][0], s1, 0,0,0);
            s1 = __builtin_amdgcn_mfma_f32_16x16x32_bf16(kA[1][1], qb[js][1], s1, 0,0,0);
            __builtin_amdgcn_s_setprio(0);

            unsigned int P0[2], P1[2];
            P0[0] = pk_fast(exp2f(s0[0]), exp2f(s0[1]));
            P0[1] = pk_fast(exp2f(s0[2]), exp2f(s0[3]));
            P1[0] = pk_fast(exp2f(s1[0]), exp2f(s1[1]));
            P1[1] = pk_fast(exp2f(s1[2]), exp2f(s1[3]));

            // wave-private C->B transpose via LDS roundtrip (no barrier)
            *(uint2*)&wts[w][lm][4 * lq]      = make_uint2(P0[0], P0[1]);
            *(uint2*)&wts[w][lm][16 + 4 * lq] = make_uint2(P1[0], P1[1]);
            s16x8 Bv = *(const s16x8*)&wts[w][lm][8 * lq];

            __builtin_amdgcn_s_setprio(1);
            #pragma unroll
            for (int cs = 0; cs < 4; ++cs)
                acc[js][cs] = __builtin_amdgcn_mfma_f32_16x16x32_bf16(
                    vA[cs], Bv, acc[js][cs], 0,0,0);
            __builtin_amdgcn_s_setprio(0);
        }
    }

    unsigned short* Up = U + ((size_t)iq * NB + b) * NPOS * CH;
    #pragma unroll
    for (int js = 0; js < 2; ++js)
        #pragma unroll
        for (int cs = 0; cs < 4; ++cs) {
            uint2 st = make_uint2(pk_rne(acc[js][cs][0], acc[js][cs][1]),
                                  pk_rne(acc[js][cs][2], acc[js][cs][3]));
            *(uint2*)&Up[(size_t)(j0 + w * 32 + js * 16 + lm) * CH
                         + cs * 16 + lq * 4] = st;
        }
}

// ---------------------------------------------------------------------------
// Kernel 4: post projection + residual.  (round-0 proven version, unchanged)
// ---------------------------------------------------------------------------
__global__ __launch_bounds__(256) void post_kernel(
    const float* __restrict__ x, const float* __restrict__ Wpost,
    const unsigned short* __restrict__ U, float* __restrict__ out)
{
    const int b  = blockIdx.y;
    const int p0 = blockIdx.x * 32;
    const int tid = threadIdx.x;
    const int w = tid >> 6, l = tid & 63, lm = l & 15, lq = l >> 4;
    const int psub = (w & 1) * 16, ohalf = w >> 1;
    const int p = p0 + psub + lm;
    const size_t PS = (size_t)NB * NPOS * CH;

    const unsigned short* u = U + ((size_t)b * NPOS + p) * CH;
    s16x8 Bf[2];
    #pragma unroll
    for (int ck = 0; ck < 2; ++ck) {
        float sv[8] = {};
        #pragma unroll
        for (int qq = 0; qq < 8; ++qq) {
            union { s16x8 v; unsigned short us[8]; } uu;
            uu.v = *(const s16x8*)(u + (size_t)qq * PS + ck * 32 + lq * 8);
            #pragma unroll
            for (int j = 0; j < 8; ++j) sv[j] += bf2f(uu.us[j]);
        }
        union { unsigned int u[4]; s16x8 v; } cb;
        #pragma unroll
        for (int j = 0; j < 4; ++j) cb.u[j] = pk_rne(sv[2*j], sv[2*j+1]);
        Bf[ck] = cb.v;
    }

    #pragma unroll
    for (int ot = 0; ot < 4; ++ot) {
        const int o0 = (ohalf * 4 + ot) * 16;
        f32x4 acc = {0.f, 0.f, 0.f, 0.f};
        #pragma unroll
        for (int ck = 0; ck < 2; ++ck) {
            const float* wp = Wpost + (o0 + lm) * CH + ck * 32 + lq * 8;
            union { unsigned int u[4]; s16x8 v; } ca;
            #pragma unroll
            for (int j = 0; j < 4; ++j) ca.u[j] = pk_rne(wp[2*j], wp[2*j+1]);
            acc = __builtin_amdgcn_mfma_f32_16x16x32_bf16(ca.v, Bf[ck], acc, 0,0,0);
        }
        #pragma unroll
        for (int r = 0; r < 4; ++r) {
            size_t gi = ((size_t)b * CIN + o0 + lq * 4 + r) * NPOS + p;
            out[gi] = x[gi] + acc[r];
        }
    }
}

extern "C" void kernel_launch(void* const* d_in, const int* in_sizes, int n_in,
                              void* d_out, int out_size, void* d_ws, size_t ws_size,
                              hipStream_t stream) {
    const float* x     = (const float*)d_in[0];
    const float* Wq    = (const float*)d_in[1];
    const float* Wk    = (const float*)d_in[2];
    const float* Wv    = (const float*)d_in[3];
    const float* Wpost = (const float*)d_in[4];
    float* out = (float*)d_out;

    // ws: kF(1MB) qF(1MB) vF(1MB) lpart(256KB) U(8MB bf16, 8 partials)
    unsigned short* kF = (unsigned short*)d_ws;
    unsigned short* qF = kF + (size_t)NB * NPOS * CH;
    unsigned short* vF = qF + (size_t)NB * NPOS * CH;
    float* lpart = (float*)(vF + (size_t)NB * NPOS * CH);
    unsigned short* U = (unsigned short*)(lpart + (size_t)8 * NB * NPOS);

    qkv_kernel  <<<dim3(NPOS / 16, NB),     256, 0, stream>>>(x, Wq, Wk, Wv, kF, qF, vF);
    stats_kernel<<<dim3(32, 8, NB),         256, 0, stream>>>(kF, qF, lpart);
    agg_kernel  <<<dim3(NPOS / 128, 8, NB), 256, 0, stream>>>(kF, qF, vF, lpart, U);
    post_kernel <<<dim3(NPOS / 32, NB),     256, 0, stream>>>(x, Wpost, U, out);
}

// Round 4
// 102.739 us; speedup vs baseline: 1.0652x; 1.0652x over previous
//
#include <hip/hip_runtime.h>
#include <math.h>

#define NB   2
#define CIN  128
#define CH   64
#define NPOS 4096
#define LOG2E 1.4426950408889634f

typedef __attribute__((ext_vector_type(8))) short s16x8;   // 8 bf16 (4 VGPRs)
typedef __attribute__((ext_vector_type(4))) float f32x4;

// frag-block global layouts (shorts):
//  kF/qF: FB(b, pos-tile16, kc) + lane*8 + elem   (1 KB per frag-block)
//  vF   : VB(b, c-tile16, i-tile32) + lane*8 + elem
// NOTE: kF stores k * log2(e)  (folded at projection time) so score MFMAs
// produce s*log2e and softmax exponentials are a single raw v_exp_f32.
#define FB(b,T,kc) ((((size_t)(b) * 256 + (size_t)(T)) * 2 + (size_t)(kc)) * 512)
#define VB(b,ct,it) ((((size_t)(b) * 4 + (size_t)(ct)) * 128 + (size_t)(it)) * 512)

__device__ __forceinline__ unsigned int bfrne(float f) {
    unsigned int u = __float_as_uint(f);
    return (u + 0x7FFFu + ((u >> 16) & 1u)) >> 16;
}
__device__ __forceinline__ unsigned int pk_rne(float lo, float hi) {
    return bfrne(lo) | (bfrne(hi) << 16);
}
// fast half-up pack for non-negative values (exp outputs)
__device__ __forceinline__ unsigned int pk_fast(float lo, float hi) {
    unsigned int a = (__float_as_uint(lo) + 0x8000u) >> 16;
    unsigned int b = (__float_as_uint(hi) + 0x8000u) & 0xFFFF0000u;
    return a | b;
}
__device__ __forceinline__ float bf2f(unsigned short h) {
    return __uint_as_float(((unsigned int)h) << 16);
}
// RAW hardware 2^x — exactly one v_exp_f32, no OCML wrapper.
// (Round-3 lesson: plain exp2f() lowers to the IEEE OCML path, ~6-10 VALU
// ops per call; __expf is 2 ops; this builtin is 1.)
__device__ __forceinline__ float hexp2(float x) {
    return __builtin_amdgcn_exp2f(x);
}

// ---------------------------------------------------------------------------
// Kernel 1: q/k/v projections via MFMA, outputs in frag-block layouts.
// Wk rows are scaled by log2(e) while packing (uniform per-tile multiplier).
// ---------------------------------------------------------------------------
#define XTS 132
__global__ __launch_bounds__(256) void qkv_kernel(
    const float* __restrict__ x,
    const float* __restrict__ Wq, const float* __restrict__ Wk,
    const float* __restrict__ Wv,
    unsigned short* __restrict__ kF, unsigned short* __restrict__ qF,
    unsigned short* __restrict__ vF)
{
    __shared__ __align__(16) float xT[16 * XTS];   // 8.25 KB
    const int b  = blockIdx.y;
    const int pt = blockIdx.x;                     // 16-pos tile index
    const int p0 = pt * 16;
    const int tid = threadIdx.x;

    #pragma unroll
    for (int it = 0; it < 2; ++it) {
        int idx = it * 256 + tid;                  // 0..511
        int c = idx >> 2, p4 = (idx & 3) * 4;
        float4 g = *(const float4*)&x[((size_t)b * CIN + c) * NPOS + p0 + p4];
        xT[(p4 + 0) * XTS + c] = g.x;
        xT[(p4 + 1) * XTS + c] = g.y;
        xT[(p4 + 2) * XTS + c] = g.z;
        xT[(p4 + 3) * XTS + c] = g.w;
    }
    __syncthreads();

    const int w = tid >> 6, l = tid & 63, lm = l & 15, lq = l >> 4;

    s16x8 Bhi[4], Blo[4];
    #pragma unroll
    for (int ck = 0; ck < 4; ++ck) {
        const float* xr = &xT[lm * XTS + ck * 32 + lq * 8];
        union { unsigned int u[4]; s16x8 v; } chv, clv;
        #pragma unroll
        for (int j = 0; j < 4; ++j) {
            float x0 = xr[2 * j], x1 = xr[2 * j + 1];
            unsigned int h0 = bfrne(x0), h1 = bfrne(x1);
            chv.u[j] = h0 | (h1 << 16);
            clv.u[j] = pk_rne(x0 - __uint_as_float(h0 << 16),
                              x1 - __uint_as_float(h1 << 16));
        }
        Bhi[ck] = chv.v; Blo[ck] = clv.v;
    }

    #pragma unroll
    for (int t3 = 0; t3 < 3; ++t3) {
        const int tile = w * 3 + t3;
        const int mat = tile >> 2, o0 = (tile & 3) * 16;
        const float* __restrict__ W = (mat == 0) ? Wq : (mat == 1) ? Wk : Wv;
        const float km = (mat == 1) ? LOG2E : 1.0f;   // fold log2e into k
        f32x4 acc = {0.f, 0.f, 0.f, 0.f};
        #pragma unroll
        for (int ck = 0; ck < 4; ++ck) {
            const float* wp = W + (o0 + lm) * CIN + ck * 32 + lq * 8;
            union { unsigned int u[4]; s16x8 v; } ca;
            #pragma unroll
            for (int j = 0; j < 4; ++j)
                ca.u[j] = pk_rne(wp[2*j] * km, wp[2*j+1] * km);
            acc = __builtin_amdgcn_mfma_f32_16x16x32_bf16(ca.v, Bhi[ck], acc, 0,0,0);
            acc = __builtin_amdgcn_mfma_f32_16x16x32_bf16(ca.v, Blo[ck], acc, 0,0,0);
        }
        // C-frag: value at (c = o0 + 4*lq + r, p = p0 + lm)
        if (mat < 2) {
            unsigned short* dst = (mat == 0) ? qF : kF;
            const int kc = o0 >> 5;
            const int lane2 = lm + 16 * (((o0 & 31) >> 3) + (lq >> 1));
            uint2 st = make_uint2(pk_rne(acc[0], acc[1]), pk_rne(acc[2], acc[3]));
            *(uint2*)&dst[FB(b, pt, kc) + lane2 * 8 + (lq & 1) * 4] = st;
        } else {
            const int ct = o0 >> 4;
            const int itile = pt >> 1;
            const int lanebase = 16 * ((pt & 1) * 2 + (lm >> 3));
            #pragma unroll
            for (int r = 0; r < 4; ++r)
                vF[VB(b, ct, itile) + (size_t)(4 * lq + r + lanebase) * 8
                   + (lm & 7)] = (unsigned short)bfrne(acc[r]);
        }
    }
}

// ---------------------------------------------------------------------------
// Kernel 2: softmax denominator partials over j-EIGHTHS.  Grid (32, 8, b)
// = 512 blocks.  Each WAVE independently owns one 32-i tile (it = bx*4+w)
// and sweeps its 512-j slice: NO LDS, NO barriers — every fragment is one
// coalesced b128 load from kF/qF.  Prefetch depth 2 (unroll-by-2 ping-pong).
// Scores arrive pre-scaled by log2e (kF fold): exponential = 1x v_exp_f32.
// ---------------------------------------------------------------------------
__global__ __launch_bounds__(256, 4) void stats_kernel(
    const unsigned short* __restrict__ kF,
    const unsigned short* __restrict__ qF,
    float* __restrict__ lpart)
{
    const int b  = blockIdx.z;
    const int jq = blockIdx.y;
    const int tid = threadIdx.x;
    const int w = tid >> 6, l = tid & 63, lm = l & 15, lq = l >> 4;
    const int it = blockIdx.x * 4 + w;             // 32-i tile, 0..127

    s16x8 a[2][2];
    #pragma unroll
    for (int s = 0; s < 2; ++s)
        #pragma unroll
        for (int kc = 0; kc < 2; ++kc)
            a[s][kc] = *(const s16x8*)&kF[FB(b, it * 2 + s, kc) + l * 8];

    const unsigned short* q0 = qF + FB(b, jq * 32, 0);   // 32 j-tiles, 1 KB each kc
    s16x8 nb0[2], nb1[2];
    nb0[0] = *(const s16x8*)&q0[l * 8];
    nb0[1] = *(const s16x8*)&q0[512 + l * 8];
    nb1[0] = *(const s16x8*)&q0[1024 + l * 8];
    nb1[1] = *(const s16x8*)&q0[1024 + 512 + l * 8];

    float rs[2][4] = {};
    #pragma unroll 1
    for (int t = 0; t < 32; t += 2) {
        // sub-iter A: j-tile t (from nb0); prefetch t+2 into nb0
        {
            s16x8 b0 = nb0[0], b1 = nb0[1];
            if (t < 30) {
                nb0[0] = *(const s16x8*)&q0[(size_t)(t + 2) * 1024 + l * 8];
                nb0[1] = *(const s16x8*)&q0[(size_t)(t + 2) * 1024 + 512 + l * 8];
            }
            #pragma unroll
            for (int s = 0; s < 2; ++s) {
                f32x4 sc = {0.f, 0.f, 0.f, 0.f};
                sc = __builtin_amdgcn_mfma_f32_16x16x32_bf16(a[s][0], b0, sc, 0,0,0);
                sc = __builtin_amdgcn_mfma_f32_16x16x32_bf16(a[s][1], b1, sc, 0,0,0);
                rs[s][0] += hexp2(sc[0]); rs[s][1] += hexp2(sc[1]);
                rs[s][2] += hexp2(sc[2]); rs[s][3] += hexp2(sc[3]);
            }
        }
        // sub-iter B: j-tile t+1 (from nb1); prefetch t+3 into nb1
        {
            s16x8 b0 = nb1[0], b1 = nb1[1];
            if (t < 30) {
                nb1[0] = *(const s16x8*)&q0[(size_t)(t + 3) * 1024 + l * 8];
                nb1[1] = *(const s16x8*)&q0[(size_t)(t + 3) * 1024 + 512 + l * 8];
            }
            #pragma unroll
            for (int s = 0; s < 2; ++s) {
                f32x4 sc = {0.f, 0.f, 0.f, 0.f};
                sc = __builtin_amdgcn_mfma_f32_16x16x32_bf16(a[s][0], b0, sc, 0,0,0);
                sc = __builtin_amdgcn_mfma_f32_16x16x32_bf16(a[s][1], b1, sc, 0,0,0);
                rs[s][0] += hexp2(sc[0]); rs[s][1] += hexp2(sc[1]);
                rs[s][2] += hexp2(sc[2]); rs[s][3] += hexp2(sc[3]);
            }
        }
    }

    #pragma unroll
    for (int s = 0; s < 2; ++s)
        #pragma unroll
        for (int r = 0; r < 4; ++r) {
            rs[s][r] += __shfl_xor(rs[s][r], 1);
            rs[s][r] += __shfl_xor(rs[s][r], 2);
            rs[s][r] += __shfl_xor(rs[s][r], 4);
            rs[s][r] += __shfl_xor(rs[s][r], 8);
        }
    if (lm == 0) {
        #pragma unroll
        for (int s = 0; s < 2; ++s)
            #pragma unroll
            for (int r = 0; r < 4; ++r)
                lpart[(size_t)jq * NB * NPOS + b * NPOS
                      + it * 32 + s * 16 + lq * 4 + r] = rs[s][r];
    }
}

// ---------------------------------------------------------------------------
// Kernel 3: aggregation over i-EIGHTHS.  Grid (32, 8, b) = 512 blocks.
// rls stores -log2(l[i]); score-MFMA C-init = -log2(l) broadcast per i-row,
// so P = exp2(s*log2e - log2 l) = exp(s)/l — one raw v_exp_f32, zero muls.
// s_setprio(1) around MFMA clusters (barrier-free independent waves).
// ---------------------------------------------------------------------------
__global__ __launch_bounds__(256, 3) void agg_kernel(
    const unsigned short* __restrict__ kF,
    const unsigned short* __restrict__ qF,
    const unsigned short* __restrict__ vF,
    const float* __restrict__ lpart,
    unsigned short* __restrict__ U)
{
    __shared__ __align__(16) unsigned short wts[4][16][40];  // 5 KB
    __shared__ __align__(16) float rls[512];                 // 2 KB
    const int b  = blockIdx.z;
    const int iq = blockIdx.y;
    const int j0 = blockIdx.x * 128;
    const int tid = threadIdx.x;
    const int w = tid >> 6, l = tid & 63, lm = l & 15, lq = l >> 4;

    // inline gl: reduce 8 lpart partials for this block's 512-i slice,
    // store NEGATED LOG2 of the denominator
    {
        const float* lp = lpart + (size_t)b * NPOS + iq * 512 + tid * 2;
        float s0 = 0.f, s1 = 0.f;
        #pragma unroll
        for (int qq = 0; qq < 8; ++qq) {
            float2 lv = *(const float2*)(lp + (size_t)qq * NB * NPOS);
            s0 += lv.x; s1 += lv.y;
        }
        rls[tid * 2 + 0] = -__log2f(s0);
        rls[tid * 2 + 1] = -__log2f(s1);
    }

    s16x8 qb[2][2];
    #pragma unroll
    for (int js = 0; js < 2; ++js)
        #pragma unroll
        for (int kc = 0; kc < 2; ++kc)
            qb[js][kc] = *(const s16x8*)&qF[
                FB(b, blockIdx.x * 8 + w * 2 + js, kc) + l * 8];

    f32x4 acc[2][4] = {};
    s16x8 nk[2][2], nv[4];
    #pragma unroll
    for (int s = 0; s < 2; ++s)
        #pragma unroll
        for (int kc = 0; kc < 2; ++kc)
            nk[s][kc] = *(const s16x8*)&kF[FB(b, iq * 32 + s, kc) + l * 8];
    #pragma unroll
    for (int cs = 0; cs < 4; ++cs)
        nv[cs] = *(const s16x8*)&vF[VB(b, cs, iq * 16) + l * 8];

    __syncthreads();   // rls ready (only barrier)

    for (int t = 0; t < 16; ++t) {
        s16x8 kA[2][2] = {{nk[0][0], nk[0][1]}, {nk[1][0], nk[1][1]}};
        s16x8 vA[4] = {nv[0], nv[1], nv[2], nv[3]};
        if (t < 15) {
            #pragma unroll
            for (int s = 0; s < 2; ++s)
                #pragma unroll
                for (int kc = 0; kc < 2; ++kc)
                    nk[s][kc] = *(const s16x8*)&kF[
                        FB(b, iq * 32 + (t + 1) * 2 + s, kc) + l * 8];
            #pragma unroll
            for (int cs = 0; cs < 4; ++cs)
                nv[cs] = *(const s16x8*)&vF[VB(b, cs, iq * 16 + t + 1) + l * 8];
        }

        f32x4 nl0 = *(const f32x4*)&rls[t * 32 + lq * 4];
        f32x4 nl1 = *(const f32x4*)&rls[t * 32 + 16 + lq * 4];

        #pragma unroll
        for (int js = 0; js < 2; ++js) {
            f32x4 s0 = nl0, s1 = nl1;   // C-init = -log2(l[i]) per i-row
            __builtin_amdgcn_s_setprio(1);
            s0 = __builtin_amdgcn_mfma_f32_16x16x32_bf16(kA[0][0], qb[js][0], s0, 0,0,0);
            s0 = __builtin_amdgcn_mfma_f32_16x16x32_bf16(kA[0][1], qb[js][1], s0, 0,0,0);
            s1 = __builtin_amdgcn_mfma_f32_16x16x32_bf16(kA[1][0], qb[js][0], s1, 0,0,0);
            s1 = __builtin_amdgcn_mfma_f32_16x16x32_bf16(kA[1][1], qb[js][1], s1, 0,0,0);
            __builtin_amdgcn_s_setprio(0);

            unsigned int P0[2], P1[2];
            P0[0] = pk_fast(hexp2(s0[0]), hexp2(s0[1]));
            P0[1] = pk_fast(hexp2(s0[2]), hexp2(s0[3]));
            P1[0] = pk_fast(hexp2(s1[0]), hexp2(s1[1]));
            P1[1] = pk_fast(hexp2(s1[2]), hexp2(s1[3]));

            // wave-private C->B transpose via LDS roundtrip (no barrier)
            *(uint2*)&wts[w][lm][4 * lq]      = make_uint2(P0[0], P0[1]);
            *(uint2*)&wts[w][lm][16 + 4 * lq] = make_uint2(P1[0], P1[1]);
            s16x8 Bv = *(const s16x8*)&wts[w][lm][8 * lq];

            __builtin_amdgcn_s_setprio(1);
            #pragma unroll
            for (int cs = 0; cs < 4; ++cs)
                acc[js][cs] = __builtin_amdgcn_mfma_f32_16x16x32_bf16(
                    vA[cs], Bv, acc[js][cs], 0,0,0);
            __builtin_amdgcn_s_setprio(0);
        }
    }

    unsigned short* Up = U + ((size_t)iq * NB + b) * NPOS * CH;
    #pragma unroll
    for (int js = 0; js < 2; ++js)
        #pragma unroll
        for (int cs = 0; cs < 4; ++cs) {
            uint2 st = make_uint2(pk_rne(acc[js][cs][0], acc[js][cs][1]),
                                  pk_rne(acc[js][cs][2], acc[js][cs][3]));
            *(uint2*)&Up[(size_t)(j0 + w * 32 + js * 16 + lm) * CH
                         + cs * 16 + lq * 4] = st;
        }
}

// ---------------------------------------------------------------------------
// Kernel 4: post projection + residual.  (round-0 proven version, unchanged)
// ---------------------------------------------------------------------------
__global__ __launch_bounds__(256) void post_kernel(
    const float* __restrict__ x, const float* __restrict__ Wpost,
    const unsigned short* __restrict__ U, float* __restrict__ out)
{
    const int b  = blockIdx.y;
    const int p0 = blockIdx.x * 32;
    const int tid = threadIdx.x;
    const int w = tid >> 6, l = tid & 63, lm = l & 15, lq = l >> 4;
    const int psub = (w & 1) * 16, ohalf = w >> 1;
    const int p = p0 + psub + lm;
    const size_t PS = (size_t)NB * NPOS * CH;

    const unsigned short* u = U + ((size_t)b * NPOS + p) * CH;
    s16x8 Bf[2];
    #pragma unroll
    for (int ck = 0; ck < 2; ++ck) {
        float sv[8] = {};
        #pragma unroll
        for (int qq = 0; qq < 8; ++qq) {
            union { s16x8 v; unsigned short us[8]; } uu;
            uu.v = *(const s16x8*)(u + (size_t)qq * PS + ck * 32 + lq * 8);
            #pragma unroll
            for (int j = 0; j < 8; ++j) sv[j] += bf2f(uu.us[j]);
        }
        union { unsigned int u[4]; s16x8 v; } cb;
        #pragma unroll
        for (int j = 0; j < 4; ++j) cb.u[j] = pk_rne(sv[2*j], sv[2*j+1]);
        Bf[ck] = cb.v;
    }

    #pragma unroll
    for (int ot = 0; ot < 4; ++ot) {
        const int o0 = (ohalf * 4 + ot) * 16;
        f32x4 acc = {0.f, 0.f, 0.f, 0.f};
        #pragma unroll
        for (int ck = 0; ck < 2; ++ck) {
            const float* wp = Wpost + (o0 + lm) * CH + ck * 32 + lq * 8;
            union { unsigned int u[4]; s16x8 v; } ca;
            #pragma unroll
            for (int j = 0; j < 4; ++j) ca.u[j] = pk_rne(wp[2*j], wp[2*j+1]);
            acc = __builtin_amdgcn_mfma_f32_16x16x32_bf16(ca.v, Bf[ck], acc, 0,0,0);
        }
        #pragma unroll
        for (int r = 0; r < 4; ++r) {
            size_t gi = ((size_t)b * CIN + o0 + lq * 4 + r) * NPOS + p;
            out[gi] = x[gi] + acc[r];
        }
    }
}

extern "C" void kernel_launch(void* const* d_in, const int* in_sizes, int n_in,
                              void* d_out, int out_size, void* d_ws, size_t ws_size,
                              hipStream_t stream) {
    const float* x     = (const float*)d_in[0];
    const float* Wq    = (const float*)d_in[1];
    const float* Wk    = (const float*)d_in[2];
    const float* Wv    = (const float*)d_in[3];
    const float* Wpost = (const float*)d_in[4];
    float* out = (float*)d_out;

    // ws: kF(1MB) qF(1MB) vF(1MB) lpart(256KB) U(8MB bf16, 8 partials)
    unsigned short* kF = (unsigned short*)d_ws;
    unsigned short* qF = kF + (size_t)NB * NPOS * CH;
    unsigned short* vF = qF + (size_t)NB * NPOS * CH;
    float* lpart = (float*)(vF + (size_t)NB * NPOS * CH);
    unsigned short* U = (unsigned short*)(lpart + (size_t)8 * NB * NPOS);

    qkv_kernel  <<<dim3(NPOS / 16, NB),     256, 0, stream>>>(x, Wq, Wk, Wv, kF, qF, vF);
    stats_kernel<<<dim3(32, 8, NB),         256, 0, stream>>>(kF, qF, lpart);
    agg_kernel  <<<dim3(NPOS / 128, 8, NB), 256, 0, stream>>>(kF, qF, vF, lpart, U);
    post_kernel <<<dim3(NPOS / 32, NB),     256, 0, stream>>>(x, Wpost, U, out);
}

// Round 5
// 100.077 us; speedup vs baseline: 1.0935x; 1.0266x over previous
//
#include <hip/hip_runtime.h>
#include <math.h>

#define NB   2
#define CIN  128
#define CH   64
#define NPOS 4096
#define JQ   16   // j-split in stats (round-5: isolated re-test of 16)
#define LOG2E 1.4426950408889634f

typedef __attribute__((ext_vector_type(8))) short s16x8;   // 8 bf16 (4 VGPRs)
typedef __attribute__((ext_vector_type(4))) float f32x4;

// frag-block global layouts (shorts):
//  kF/qF: FB(b, pos-tile16, kc) + lane*8 + elem   (1 KB per frag-block)
//  vF   : VB(b, c-tile16, i-tile32) + lane*8 + elem
// NOTE: kF stores k * log2(e)  (folded at projection time) so score MFMAs
// produce s*log2e and softmax exponentials are a single raw v_exp_f32.
#define FB(b,T,kc) ((((size_t)(b) * 256 + (size_t)(T)) * 2 + (size_t)(kc)) * 512)
#define VB(b,ct,it) ((((size_t)(b) * 4 + (size_t)(ct)) * 128 + (size_t)(it)) * 512)

__device__ __forceinline__ unsigned int bfrne(float f) {
    unsigned int u = __float_as_uint(f);
    return (u + 0x7FFFu + ((u >> 16) & 1u)) >> 16;
}
__device__ __forceinline__ unsigned int pk_rne(float lo, float hi) {
    return bfrne(lo) | (bfrne(hi) << 16);
}
// fast half-up pack for non-negative values (exp outputs)
__device__ __forceinline__ unsigned int pk_fast(float lo, float hi) {
    unsigned int a = (__float_as_uint(lo) + 0x8000u) >> 16;
    unsigned int b = (__float_as_uint(hi) + 0x8000u) & 0xFFFF0000u;
    return a | b;
}
__device__ __forceinline__ float bf2f(unsigned short h) {
    return __uint_as_float(((unsigned int)h) << 16);
}
// RAW hardware 2^x — exactly one v_exp_f32, no OCML wrapper.
// (Round-3 lesson: plain exp2f() lowers to the IEEE OCML path, ~6-10 VALU
// ops per call; __expf is 2 ops; this builtin is 1.)
__device__ __forceinline__ float hexp2(float x) {
    return __builtin_amdgcn_exp2f(x);
}

// ---------------------------------------------------------------------------
// Kernel 1: q/k/v projections via MFMA, outputs in frag-block layouts.
// Wk rows are scaled by log2(e) while packing.  (round-4 proven, unchanged)
// ---------------------------------------------------------------------------
#define XTS 132
__global__ __launch_bounds__(256) void qkv_kernel(
    const float* __restrict__ x,
    const float* __restrict__ Wq, const float* __restrict__ Wk,
    const float* __restrict__ Wv,
    unsigned short* __restrict__ kF, unsigned short* __restrict__ qF,
    unsigned short* __restrict__ vF)
{
    __shared__ __align__(16) float xT[16 * XTS];   // 8.25 KB
    const int b  = blockIdx.y;
    const int pt = blockIdx.x;                     // 16-pos tile index
    const int p0 = pt * 16;
    const int tid = threadIdx.x;

    #pragma unroll
    for (int it = 0; it < 2; ++it) {
        int idx = it * 256 + tid;                  // 0..511
        int c = idx >> 2, p4 = (idx & 3) * 4;
        float4 g = *(const float4*)&x[((size_t)b * CIN + c) * NPOS + p0 + p4];
        xT[(p4 + 0) * XTS + c] = g.x;
        xT[(p4 + 1) * XTS + c] = g.y;
        xT[(p4 + 2) * XTS + c] = g.z;
        xT[(p4 + 3) * XTS + c] = g.w;
    }
    __syncthreads();

    const int w = tid >> 6, l = tid & 63, lm = l & 15, lq = l >> 4;

    s16x8 Bhi[4], Blo[4];
    #pragma unroll
    for (int ck = 0; ck < 4; ++ck) {
        const float* xr = &xT[lm * XTS + ck * 32 + lq * 8];
        union { unsigned int u[4]; s16x8 v; } chv, clv;
        #pragma unroll
        for (int j = 0; j < 4; ++j) {
            float x0 = xr[2 * j], x1 = xr[2 * j + 1];
            unsigned int h0 = bfrne(x0), h1 = bfrne(x1);
            chv.u[j] = h0 | (h1 << 16);
            clv.u[j] = pk_rne(x0 - __uint_as_float(h0 << 16),
                              x1 - __uint_as_float(h1 << 16));
        }
        Bhi[ck] = chv.v; Blo[ck] = clv.v;
    }

    #pragma unroll
    for (int t3 = 0; t3 < 3; ++t3) {
        const int tile = w * 3 + t3;
        const int mat = tile >> 2, o0 = (tile & 3) * 16;
        const float* __restrict__ W = (mat == 0) ? Wq : (mat == 1) ? Wk : Wv;
        const float km = (mat == 1) ? LOG2E : 1.0f;   // fold log2e into k
        f32x4 acc = {0.f, 0.f, 0.f, 0.f};
        #pragma unroll
        for (int ck = 0; ck < 4; ++ck) {
            const float* wp = W + (o0 + lm) * CIN + ck * 32 + lq * 8;
            union { unsigned int u[4]; s16x8 v; } ca;
            #pragma unroll
            for (int j = 0; j < 4; ++j)
                ca.u[j] = pk_rne(wp[2*j] * km, wp[2*j+1] * km);
            acc = __builtin_amdgcn_mfma_f32_16x16x32_bf16(ca.v, Bhi[ck], acc, 0,0,0);
            acc = __builtin_amdgcn_mfma_f32_16x16x32_bf16(ca.v, Blo[ck], acc, 0,0,0);
        }
        // C-frag: value at (c = o0 + 4*lq + r, p = p0 + lm)
        if (mat < 2) {
            unsigned short* dst = (mat == 0) ? qF : kF;
            const int kc = o0 >> 5;
            const int lane2 = lm + 16 * (((o0 & 31) >> 3) + (lq >> 1));
            uint2 st = make_uint2(pk_rne(acc[0], acc[1]), pk_rne(acc[2], acc[3]));
            *(uint2*)&dst[FB(b, pt, kc) + lane2 * 8 + (lq & 1) * 4] = st;
        } else {
            const int ct = o0 >> 4;
            const int itile = pt >> 1;
            const int lanebase = 16 * ((pt & 1) * 2 + (lm >> 3));
            #pragma unroll
            for (int r = 0; r < 4; ++r)
                vF[VB(b, ct, itile) + (size_t)(4 * lq + r + lanebase) * 8
                   + (lm & 7)] = (unsigned short)bfrne(acc[r]);
        }
    }
}

// ---------------------------------------------------------------------------
// Kernel 2: softmax denominator partials over j-SIXTEENTHS.  Grid (32,16,b)
// = 1024 blocks (4 waves/SIMD — round-5: isolated TLP bump so the trans
// (v_exp) / VALU (add) / MFMA pipes can overlap across waves).  Each WAVE
// independently owns one 32-i tile and sweeps its 256-j slice: NO LDS, NO
// barriers.  Prefetch depth 2 (ping-pong, static names).  Exponential =
// one raw v_exp_f32 (kF pre-scaled by log2e).
// ---------------------------------------------------------------------------
__global__ __launch_bounds__(256, 4) void stats_kernel(
    const unsigned short* __restrict__ kF,
    const unsigned short* __restrict__ qF,
    float* __restrict__ lpart)
{
    const int b  = blockIdx.z;
    const int jq = blockIdx.y;                     // 0..15
    const int tid = threadIdx.x;
    const int w = tid >> 6, l = tid & 63, lm = l & 15, lq = l >> 4;
    const int it = blockIdx.x * 4 + w;             // 32-i tile, 0..127

    s16x8 a[2][2];
    #pragma unroll
    for (int s = 0; s < 2; ++s)
        #pragma unroll
        for (int kc = 0; kc < 2; ++kc)
            a[s][kc] = *(const s16x8*)&kF[FB(b, it * 2 + s, kc) + l * 8];

    const unsigned short* q0 = qF + FB(b, jq * 16, 0);   // 16 j-tiles, 1 KB each kc
    s16x8 nb0[2], nb1[2];
    nb0[0] = *(const s16x8*)&q0[l * 8];
    nb0[1] = *(const s16x8*)&q0[512 + l * 8];
    nb1[0] = *(const s16x8*)&q0[1024 + l * 8];
    nb1[1] = *(const s16x8*)&q0[1024 + 512 + l * 8];

    float rs[2][4] = {};
    #pragma unroll 1
    for (int t = 0; t < 16; t += 2) {
        // sub-iter A: j-tile t (from nb0); prefetch t+2 into nb0
        {
            s16x8 b0 = nb0[0], b1 = nb0[1];
            if (t < 14) {
                nb0[0] = *(const s16x8*)&q0[(size_t)(t + 2) * 1024 + l * 8];
                nb0[1] = *(const s16x8*)&q0[(size_t)(t + 2) * 1024 + 512 + l * 8];
            }
            #pragma unroll
            for (int s = 0; s < 2; ++s) {
                f32x4 sc = {0.f, 0.f, 0.f, 0.f};
                sc = __builtin_amdgcn_mfma_f32_16x16x32_bf16(a[s][0], b0, sc, 0,0,0);
                sc = __builtin_amdgcn_mfma_f32_16x16x32_bf16(a[s][1], b1, sc, 0,0,0);
                rs[s][0] += hexp2(sc[0]); rs[s][1] += hexp2(sc[1]);
                rs[s][2] += hexp2(sc[2]); rs[s][3] += hexp2(sc[3]);
            }
        }
        // sub-iter B: j-tile t+1 (from nb1); prefetch t+3 into nb1
        {
            s16x8 b0 = nb1[0], b1 = nb1[1];
            if (t < 14) {
                nb1[0] = *(const s16x8*)&q0[(size_t)(t + 3) * 1024 + l * 8];
                nb1[1] = *(const s16x8*)&q0[(size_t)(t + 3) * 1024 + 512 + l * 8];
            }
            #pragma unroll
            for (int s = 0; s < 2; ++s) {
                f32x4 sc = {0.f, 0.f, 0.f, 0.f};
                sc = __builtin_amdgcn_mfma_f32_16x16x32_bf16(a[s][0], b0, sc, 0,0,0);
                sc = __builtin_amdgcn_mfma_f32_16x16x32_bf16(a[s][1], b1, sc, 0,0,0);
                rs[s][0] += hexp2(sc[0]); rs[s][1] += hexp2(sc[1]);
                rs[s][2] += hexp2(sc[2]); rs[s][3] += hexp2(sc[3]);
            }
        }
    }

    #pragma unroll
    for (int s = 0; s < 2; ++s)
        #pragma unroll
        for (int r = 0; r < 4; ++r) {
            rs[s][r] += __shfl_xor(rs[s][r], 1);
            rs[s][r] += __shfl_xor(rs[s][r], 2);
            rs[s][r] += __shfl_xor(rs[s][r], 4);
            rs[s][r] += __shfl_xor(rs[s][r], 8);
        }
    if (lm == 0) {
        #pragma unroll
        for (int s = 0; s < 2; ++s)
            #pragma unroll
            for (int r = 0; r < 4; ++r)
                lpart[(size_t)jq * NB * NPOS + b * NPOS
                      + it * 32 + s * 16 + lq * 4 + r] = rs[s][r];
    }
}

// ---------------------------------------------------------------------------
// Kernel 3: aggregation over i-EIGHTHS.  Grid (32, 8, b) = 512 blocks.
// rls stores -log2(l[i]); score-MFMA C-init = -log2(l) broadcast per i-row,
// so P = exp2(s*log2e - log2 l) = exp(s)/l — one raw v_exp_f32, zero muls.
// s_setprio(1) around MFMA clusters.  (round-4 proven; only change: gl
// reduction now sums JQ=16 lpart partials.)
// ---------------------------------------------------------------------------
__global__ __launch_bounds__(256, 3) void agg_kernel(
    const unsigned short* __restrict__ kF,
    const unsigned short* __restrict__ qF,
    const unsigned short* __restrict__ vF,
    const float* __restrict__ lpart,
    unsigned short* __restrict__ U)
{
    __shared__ __align__(16) unsigned short wts[4][16][40];  // 5 KB
    __shared__ __align__(16) float rls[512];                 // 2 KB
    const int b  = blockIdx.z;
    const int iq = blockIdx.y;
    const int j0 = blockIdx.x * 128;
    const int tid = threadIdx.x;
    const int w = tid >> 6, l = tid & 63, lm = l & 15, lq = l >> 4;

    // inline gl: reduce JQ lpart partials for this block's 512-i slice,
    // store NEGATED LOG2 of the denominator
    {
        const float* lp = lpart + (size_t)b * NPOS + iq * 512 + tid * 2;
        float s0 = 0.f, s1 = 0.f;
        #pragma unroll
        for (int qq = 0; qq < JQ; ++qq) {
            float2 lv = *(const float2*)(lp + (size_t)qq * NB * NPOS);
            s0 += lv.x; s1 += lv.y;
        }
        rls[tid * 2 + 0] = -__log2f(s0);
        rls[tid * 2 + 1] = -__log2f(s1);
    }

    s16x8 qb[2][2];
    #pragma unroll
    for (int js = 0; js < 2; ++js)
        #pragma unroll
        for (int kc = 0; kc < 2; ++kc)
            qb[js][kc] = *(const s16x8*)&qF[
                FB(b, blockIdx.x * 8 + w * 2 + js, kc) + l * 8];

    f32x4 acc[2][4] = {};
    s16x8 nk[2][2], nv[4];
    #pragma unroll
    for (int s = 0; s < 2; ++s)
        #pragma unroll
        for (int kc = 0; kc < 2; ++kc)
            nk[s][kc] = *(const s16x8*)&kF[FB(b, iq * 32 + s, kc) + l * 8];
    #pragma unroll
    for (int cs = 0; cs < 4; ++cs)
        nv[cs] = *(const s16x8*)&vF[VB(b, cs, iq * 16) + l * 8];

    __syncthreads();   // rls ready (only barrier)

    for (int t = 0; t < 16; ++t) {
        s16x8 kA[2][2] = {{nk[0][0], nk[0][1]}, {nk[1][0], nk[1][1]}};
        s16x8 vA[4] = {nv[0], nv[1], nv[2], nv[3]};
        if (t < 15) {
            #pragma unroll
            for (int s = 0; s < 2; ++s)
                #pragma unroll
                for (int kc = 0; kc < 2; ++kc)
                    nk[s][kc] = *(const s16x8*)&kF[
                        FB(b, iq * 32 + (t + 1) * 2 + s, kc) + l * 8];
            #pragma unroll
            for (int cs = 0; cs < 4; ++cs)
                nv[cs] = *(const s16x8*)&vF[VB(b, cs, iq * 16 + t + 1) + l * 8];
        }

        f32x4 nl0 = *(const f32x4*)&rls[t * 32 + lq * 4];
        f32x4 nl1 = *(const f32x4*)&rls[t * 32 + 16 + lq * 4];

        #pragma unroll
        for (int js = 0; js < 2; ++js) {
            f32x4 s0 = nl0, s1 = nl1;   // C-init = -log2(l[i]) per i-row
            __builtin_amdgcn_s_setprio(1);
            s0 = __builtin_amdgcn_mfma_f32_16x16x32_bf16(kA[0][0], qb[js][0], s0, 0,0,0);
            s0 = __builtin_amdgcn_mfma_f32_16x16x32_bf16(kA[0][1], qb[js][1], s0, 0,0,0);
            s1 = __builtin_amdgcn_mfma_f32_16x16x32_bf16(kA[1][0], qb[js][0], s1, 0,0,0);
            s1 = __builtin_amdgcn_mfma_f32_16x16x32_bf16(kA[1][1], qb[js][1], s1, 0,0,0);
            __builtin_amdgcn_s_setprio(0);

            unsigned int P0[2], P1[2];
            P0[0] = pk_fast(hexp2(s0[0]), hexp2(s0[1]));
            P0[1] = pk_fast(hexp2(s0[2]), hexp2(s0[3]));
            P1[0] = pk_fast(hexp2(s1[0]), hexp2(s1[1]));
            P1[1] = pk_fast(hexp2(s1[2]), hexp2(s1[3]));

            // wave-private C->B transpose via LDS roundtrip (no barrier)
            *(uint2*)&wts[w][lm][4 * lq]      = make_uint2(P0[0], P0[1]);
            *(uint2*)&wts[w][lm][16 + 4 * lq] = make_uint2(P1[0], P1[1]);
            s16x8 Bv = *(const s16x8*)&wts[w][lm][8 * lq];

            __builtin_amdgcn_s_setprio(1);
            #pragma unroll
            for (int cs = 0; cs < 4; ++cs)
                acc[js][cs] = __builtin_amdgcn_mfma_f32_16x16x32_bf16(
                    vA[cs], Bv, acc[js][cs], 0,0,0);
            __builtin_amdgcn_s_setprio(0);
        }
    }

    unsigned short* Up = U + ((size_t)iq * NB + b) * NPOS * CH;
    #pragma unroll
    for (int js = 0; js < 2; ++js)
        #pragma unroll
        for (int cs = 0; cs < 4; ++cs) {
            uint2 st = make_uint2(pk_rne(acc[js][cs][0], acc[js][cs][1]),
                                  pk_rne(acc[js][cs][2], acc[js][cs][3]));
            *(uint2*)&Up[(size_t)(j0 + w * 32 + js * 16 + lm) * CH
                         + cs * 16 + lq * 4] = st;
        }
}

// ---------------------------------------------------------------------------
// Kernel 4: post projection + residual.  Round-5 change: cooperative U-sum.
// 256 threads sum the 8 U partials ONCE into a 4.3 KB LDS tile (thread =
// one pos x 8-channel group, coalesced b128 chain), one barrier, then each
// wave reads its B-fragments from LDS — halves U traffic (was 2x-redundant
// across wave pairs) and halves the bf2f add chain per thread.
// ---------------------------------------------------------------------------
__global__ __launch_bounds__(256) void post_kernel(
    const float* __restrict__ x, const float* __restrict__ Wpost,
    const unsigned short* __restrict__ U, float* __restrict__ out)
{
    __shared__ __align__(16) unsigned short BfL[32][68];  // 4.25 KB (pad->68)
    const int b  = blockIdx.y;
    const int p0 = blockIdx.x * 32;
    const int tid = threadIdx.x;
    const size_t PS = (size_t)NB * NPOS * CH;

    // cooperative U-sum: thread = (pos p = tid>>3, channel-group cg = tid&7)
    {
        const int p  = tid >> 3;          // 0..31
        const int cg = tid & 7;           // 0..7 -> channels cg*8..cg*8+7
        const unsigned short* u = U + ((size_t)b * NPOS + p0 + p) * CH + cg * 8;
        float sv[8] = {};
        #pragma unroll
        for (int qq = 0; qq < 8; ++qq) {
            union { s16x8 v; unsigned short us[8]; } uu;
            uu.v = *(const s16x8*)(u + (size_t)qq * PS);
            #pragma unroll
            for (int j = 0; j < 8; ++j) sv[j] += bf2f(uu.us[j]);
        }
        *(uint2*)&BfL[p][cg * 8]     = make_uint2(pk_rne(sv[0], sv[1]),
                                                  pk_rne(sv[2], sv[3]));
        *(uint2*)&BfL[p][cg * 8 + 4] = make_uint2(pk_rne(sv[4], sv[5]),
                                                  pk_rne(sv[6], sv[7]));
    }
    __syncthreads();

    const int w = tid >> 6, l = tid & 63, lm = l & 15, lq = l >> 4;
    const int psub = (w & 1) * 16, ohalf = w >> 1;
    const int p = p0 + psub + lm;

    s16x8 Bf[2];
    #pragma unroll
    for (int ck = 0; ck < 2; ++ck) {
        uint2 lo = *(const uint2*)&BfL[psub + lm][ck * 32 + lq * 8];
        uint2 hi = *(const uint2*)&BfL[psub + lm][ck * 32 + lq * 8 + 4];
        union { unsigned int u[4]; s16x8 v; } cb;
        cb.u[0] = lo.x; cb.u[1] = lo.y; cb.u[2] = hi.x; cb.u[3] = hi.y;
        Bf[ck] = cb.v;
    }

    #pragma unroll
    for (int ot = 0; ot < 4; ++ot) {
        const int o0 = (ohalf * 4 + ot) * 16;
        f32x4 acc = {0.f, 0.f, 0.f, 0.f};
        #pragma unroll
        for (int ck = 0; ck < 2; ++ck) {
            const float* wp = Wpost + (o0 + lm) * CH + ck * 32 + lq * 8;
            union { unsigned int u[4]; s16x8 v; } ca;
            #pragma unroll
            for (int j = 0; j < 4; ++j) ca.u[j] = pk_rne(wp[2*j], wp[2*j+1]);
            acc = __builtin_amdgcn_mfma_f32_16x16x32_bf16(ca.v, Bf[ck], acc, 0,0,0);
        }
        #pragma unroll
        for (int r = 0; r < 4; ++r) {
            size_t gi = ((size_t)b * CIN + o0 + lq * 4 + r) * NPOS + p;
            out[gi] = x[gi] + acc[r];
        }
    }
}

extern "C" void kernel_launch(void* const* d_in, const int* in_sizes, int n_in,
                              void* d_out, int out_size, void* d_ws, size_t ws_size,
                              hipStream_t stream) {
    const float* x     = (const float*)d_in[0];
    const float* Wq    = (const float*)d_in[1];
    const float* Wk    = (const float*)d_in[2];
    const float* Wv    = (const float*)d_in[3];
    const float* Wpost = (const float*)d_in[4];
    float* out = (float*)d_out;

    // ws: kF(1MB) qF(1MB) vF(1MB) lpart(512KB) U(8MB bf16, 8 partials)
    unsigned short* kF = (unsigned short*)d_ws;
    unsigned short* qF = kF + (size_t)NB * NPOS * CH;
    unsigned short* vF = qF + (size_t)NB * NPOS * CH;
    float* lpart = (float*)(vF + (size_t)NB * NPOS * CH);
    unsigned short* U = (unsigned short*)(lpart + (size_t)JQ * NB * NPOS);

    qkv_kernel  <<<dim3(NPOS / 16, NB),     256, 0, stream>>>(x, Wq, Wk, Wv, kF, qF, vF);
    stats_kernel<<<dim3(32, JQ, NB),        256, 0, stream>>>(kF, qF, lpart);
    agg_kernel  <<<dim3(NPOS / 128, 8, NB), 256, 0, stream>>>(kF, qF, vF, lpart, U);
    post_kernel <<<dim3(NPOS / 32, NB),     256, 0, stream>>>(x, Wpost, U, out);
}

// Round 6
// 99.373 us; speedup vs baseline: 1.1013x; 1.0071x over previous
//
#include <hip/hip_runtime.h>
#include <math.h>

#define NB   2
#define CIN  128
#define CH   64
#define NPOS 4096
#define JQ   16   // j-split in stats
#define LOG2E 1.4426950408889634f

typedef __attribute__((ext_vector_type(8))) short s16x8;   // 8 bf16 (4 VGPRs)
typedef __attribute__((ext_vector_type(4))) float f32x4;

// frag-block global layouts (shorts):
//  kF/qF: FB(b, pos-tile16, kc) + lane*8 + elem   (1 KB per frag-block)
//  vF   : VB(b, c-tile16, i-tile32) + lane*8 + elem
// NOTE: kF stores k * log2(e)  (folded at projection time) so score MFMAs
// produce s*log2e and softmax exponentials are a single raw v_exp_f32.
#define FB(b,T,kc) ((((size_t)(b) * 256 + (size_t)(T)) * 2 + (size_t)(kc)) * 512)
#define VB(b,ct,it) ((((size_t)(b) * 4 + (size_t)(ct)) * 128 + (size_t)(it)) * 512)

__device__ __forceinline__ unsigned int bfrne(float f) {
    unsigned int u = __float_as_uint(f);
    return (u + 0x7FFFu + ((u >> 16) & 1u)) >> 16;
}
__device__ __forceinline__ unsigned int pk_rne(float lo, float hi) {
    return bfrne(lo) | (bfrne(hi) << 16);
}
// fast half-up pack for non-negative values (exp outputs)
__device__ __forceinline__ unsigned int pk_fast(float lo, float hi) {
    unsigned int a = (__float_as_uint(lo) + 0x8000u) >> 16;
    unsigned int b = (__float_as_uint(hi) + 0x8000u) & 0xFFFF0000u;
    return a | b;
}
__device__ __forceinline__ float bf2f(unsigned short h) {
    return __uint_as_float(((unsigned int)h) << 16);
}
// RAW hardware 2^x — exactly one v_exp_f32, no OCML wrapper.
// (Round-3 lesson: plain exp2f() lowers to the IEEE OCML path, ~6-10 VALU
// ops per call; __expf is 2 ops; this builtin is 1.)
__device__ __forceinline__ float hexp2(float x) {
    return __builtin_amdgcn_exp2f(x);
}

// ---------------------------------------------------------------------------
// Kernel 1: q/k/v projections via MFMA, outputs in frag-block layouts.
// Wk rows are scaled by log2(e) while packing.  (round-4 proven, unchanged)
// ---------------------------------------------------------------------------
#define XTS 132
__global__ __launch_bounds__(256) void qkv_kernel(
    const float* __restrict__ x,
    const float* __restrict__ Wq, const float* __restrict__ Wk,
    const float* __restrict__ Wv,
    unsigned short* __restrict__ kF, unsigned short* __restrict__ qF,
    unsigned short* __restrict__ vF)
{
    __shared__ __align__(16) float xT[16 * XTS];   // 8.25 KB
    const int b  = blockIdx.y;
    const int pt = blockIdx.x;                     // 16-pos tile index
    const int p0 = pt * 16;
    const int tid = threadIdx.x;

    #pragma unroll
    for (int it = 0; it < 2; ++it) {
        int idx = it * 256 + tid;                  // 0..511
        int c = idx >> 2, p4 = (idx & 3) * 4;
        float4 g = *(const float4*)&x[((size_t)b * CIN + c) * NPOS + p0 + p4];
        xT[(p4 + 0) * XTS + c] = g.x;
        xT[(p4 + 1) * XTS + c] = g.y;
        xT[(p4 + 2) * XTS + c] = g.z;
        xT[(p4 + 3) * XTS + c] = g.w;
    }
    __syncthreads();

    const int w = tid >> 6, l = tid & 63, lm = l & 15, lq = l >> 4;

    s16x8 Bhi[4], Blo[4];
    #pragma unroll
    for (int ck = 0; ck < 4; ++ck) {
        const float* xr = &xT[lm * XTS + ck * 32 + lq * 8];
        union { unsigned int u[4]; s16x8 v; } chv, clv;
        #pragma unroll
        for (int j = 0; j < 4; ++j) {
            float x0 = xr[2 * j], x1 = xr[2 * j + 1];
            unsigned int h0 = bfrne(x0), h1 = bfrne(x1);
            chv.u[j] = h0 | (h1 << 16);
            clv.u[j] = pk_rne(x0 - __uint_as_float(h0 << 16),
                              x1 - __uint_as_float(h1 << 16));
        }
        Bhi[ck] = chv.v; Blo[ck] = clv.v;
    }

    #pragma unroll
    for (int t3 = 0; t3 < 3; ++t3) {
        const int tile = w * 3 + t3;
        const int mat = tile >> 2, o0 = (tile & 3) * 16;
        const float* __restrict__ W = (mat == 0) ? Wq : (mat == 1) ? Wk : Wv;
        const float km = (mat == 1) ? LOG2E : 1.0f;   // fold log2e into k
        f32x4 acc = {0.f, 0.f, 0.f, 0.f};
        #pragma unroll
        for (int ck = 0; ck < 4; ++ck) {
            const float* wp = W + (o0 + lm) * CIN + ck * 32 + lq * 8;
            union { unsigned int u[4]; s16x8 v; } ca;
            #pragma unroll
            for (int j = 0; j < 4; ++j)
                ca.u[j] = pk_rne(wp[2*j] * km, wp[2*j+1] * km);
            acc = __builtin_amdgcn_mfma_f32_16x16x32_bf16(ca.v, Bhi[ck], acc, 0,0,0);
            acc = __builtin_amdgcn_mfma_f32_16x16x32_bf16(ca.v, Blo[ck], acc, 0,0,0);
        }
        // C-frag: value at (c = o0 + 4*lq + r, p = p0 + lm)
        if (mat < 2) {
            unsigned short* dst = (mat == 0) ? qF : kF;
            const int kc = o0 >> 5;
            const int lane2 = lm + 16 * (((o0 & 31) >> 3) + (lq >> 1));
            uint2 st = make_uint2(pk_rne(acc[0], acc[1]), pk_rne(acc[2], acc[3]));
            *(uint2*)&dst[FB(b, pt, kc) + lane2 * 8 + (lq & 1) * 4] = st;
        } else {
            const int ct = o0 >> 4;
            const int itile = pt >> 1;
            const int lanebase = 16 * ((pt & 1) * 2 + (lm >> 3));
            #pragma unroll
            for (int r = 0; r < 4; ++r)
                vF[VB(b, ct, itile) + (size_t)(4 * lq + r + lanebase) * 8
                   + (lm & 7)] = (unsigned short)bfrne(acc[r]);
        }
    }
}

// ---------------------------------------------------------------------------
// Kernel 2: softmax denominator partials over j-SIXTEENTHS.  Grid (32,16,b)
// = 1024 blocks (4 waves/SIMD).  Each WAVE independently owns one 32-i tile
// and sweeps its 256-j slice: NO LDS, NO barriers.  Prefetch depth 2
// (ping-pong, static names).  Exponential = one raw v_exp_f32.
// (round-5 proven, unchanged)
// ---------------------------------------------------------------------------
__global__ __launch_bounds__(256, 4) void stats_kernel(
    const unsigned short* __restrict__ kF,
    const unsigned short* __restrict__ qF,
    float* __restrict__ lpart)
{
    const int b  = blockIdx.z;
    const int jq = blockIdx.y;                     // 0..15
    const int tid = threadIdx.x;
    const int w = tid >> 6, l = tid & 63, lm = l & 15, lq = l >> 4;
    const int it = blockIdx.x * 4 + w;             // 32-i tile, 0..127

    s16x8 a[2][2];
    #pragma unroll
    for (int s = 0; s < 2; ++s)
        #pragma unroll
        for (int kc = 0; kc < 2; ++kc)
            a[s][kc] = *(const s16x8*)&kF[FB(b, it * 2 + s, kc) + l * 8];

    const unsigned short* q0 = qF + FB(b, jq * 16, 0);   // 16 j-tiles, 1 KB each kc
    s16x8 nb0[2], nb1[2];
    nb0[0] = *(const s16x8*)&q0[l * 8];
    nb0[1] = *(const s16x8*)&q0[512 + l * 8];
    nb1[0] = *(const s16x8*)&q0[1024 + l * 8];
    nb1[1] = *(const s16x8*)&q0[1024 + 512 + l * 8];

    float rs[2][4] = {};
    #pragma unroll 1
    for (int t = 0; t < 16; t += 2) {
        // sub-iter A: j-tile t (from nb0); prefetch t+2 into nb0
        {
            s16x8 b0 = nb0[0], b1 = nb0[1];
            if (t < 14) {
                nb0[0] = *(const s16x8*)&q0[(size_t)(t + 2) * 1024 + l * 8];
                nb0[1] = *(const s16x8*)&q0[(size_t)(t + 2) * 1024 + 512 + l * 8];
            }
            #pragma unroll
            for (int s = 0; s < 2; ++s) {
                f32x4 sc = {0.f, 0.f, 0.f, 0.f};
                sc = __builtin_amdgcn_mfma_f32_16x16x32_bf16(a[s][0], b0, sc, 0,0,0);
                sc = __builtin_amdgcn_mfma_f32_16x16x32_bf16(a[s][1], b1, sc, 0,0,0);
                rs[s][0] += hexp2(sc[0]); rs[s][1] += hexp2(sc[1]);
                rs[s][2] += hexp2(sc[2]); rs[s][3] += hexp2(sc[3]);
            }
        }
        // sub-iter B: j-tile t+1 (from nb1); prefetch t+3 into nb1
        {
            s16x8 b0 = nb1[0], b1 = nb1[1];
            if (t < 14) {
                nb1[0] = *(const s16x8*)&q0[(size_t)(t + 3) * 1024 + l * 8];
                nb1[1] = *(const s16x8*)&q0[(size_t)(t + 3) * 1024 + 512 + l * 8];
            }
            #pragma unroll
            for (int s = 0; s < 2; ++s) {
                f32x4 sc = {0.f, 0.f, 0.f, 0.f};
                sc = __builtin_amdgcn_mfma_f32_16x16x32_bf16(a[s][0], b0, sc, 0,0,0);
                sc = __builtin_amdgcn_mfma_f32_16x16x32_bf16(a[s][1], b1, sc, 0,0,0);
                rs[s][0] += hexp2(sc[0]); rs[s][1] += hexp2(sc[1]);
                rs[s][2] += hexp2(sc[2]); rs[s][3] += hexp2(sc[3]);
            }
        }
    }

    #pragma unroll
    for (int s = 0; s < 2; ++s)
        #pragma unroll
        for (int r = 0; r < 4; ++r) {
            rs[s][r] += __shfl_xor(rs[s][r], 1);
            rs[s][r] += __shfl_xor(rs[s][r], 2);
            rs[s][r] += __shfl_xor(rs[s][r], 4);
            rs[s][r] += __shfl_xor(rs[s][r], 8);
        }
    if (lm == 0) {
        #pragma unroll
        for (int s = 0; s < 2; ++s)
            #pragma unroll
            for (int r = 0; r < 4; ++r)
                lpart[(size_t)jq * NB * NPOS + b * NPOS
                      + it * 32 + s * 16 + lq * 4 + r] = rs[s][r];
    }
}

// ---------------------------------------------------------------------------
// Kernel 3: aggregation over i-EIGHTHS.  Grid (32, 8, b) = 512 blocks
// (grid-limited to 2 blocks/CU, so launch_bounds relaxed to (256,2) —
// frees the register allocator at zero occupancy cost).
// Round-6 change (ISOLATED js-batching, de-confounded from round 1):
// per t, the two independent js chains are batched — 8 score MFMAs, then
// all 16 exps/packs, then both LDS roundtrips, then 8 PV MFMAs — doubling
// in-flight ILP on the serial MFMA->exp->pack->LDS->MFMA chain (only 2
// waves/SIMD resident to hide latency otherwise).
// rls stores -log2(l[i]); score-MFMA C-init = -log2(l) per i-row, so
// P = exp2(s*log2e - log2 l) = exp(s)/l — one raw v_exp_f32, zero muls.
// ---------------------------------------------------------------------------
__global__ __launch_bounds__(256, 2) void agg_kernel(
    const unsigned short* __restrict__ kF,
    const unsigned short* __restrict__ qF,
    const unsigned short* __restrict__ vF,
    const float* __restrict__ lpart,
    unsigned short* __restrict__ U)
{
    __shared__ __align__(16) unsigned short wts[4][2][16][40];  // 10.2 KB
    __shared__ __align__(16) float rls[512];                    // 2 KB
    const int b  = blockIdx.z;
    const int iq = blockIdx.y;
    const int j0 = blockIdx.x * 128;
    const int tid = threadIdx.x;
    const int w = tid >> 6, l = tid & 63, lm = l & 15, lq = l >> 4;

    // inline gl: reduce JQ lpart partials for this block's 512-i slice,
    // store NEGATED LOG2 of the denominator
    {
        const float* lp = lpart + (size_t)b * NPOS + iq * 512 + tid * 2;
        float s0 = 0.f, s1 = 0.f;
        #pragma unroll
        for (int qq = 0; qq < JQ; ++qq) {
            float2 lv = *(const float2*)(lp + (size_t)qq * NB * NPOS);
            s0 += lv.x; s1 += lv.y;
        }
        rls[tid * 2 + 0] = -__log2f(s0);
        rls[tid * 2 + 1] = -__log2f(s1);
    }

    s16x8 qb[2][2];
    #pragma unroll
    for (int js = 0; js < 2; ++js)
        #pragma unroll
        for (int kc = 0; kc < 2; ++kc)
            qb[js][kc] = *(const s16x8*)&qF[
                FB(b, blockIdx.x * 8 + w * 2 + js, kc) + l * 8];

    f32x4 acc[2][4] = {};
    s16x8 nk[2][2], nv[4];
    #pragma unroll
    for (int s = 0; s < 2; ++s)
        #pragma unroll
        for (int kc = 0; kc < 2; ++kc)
            nk[s][kc] = *(const s16x8*)&kF[FB(b, iq * 32 + s, kc) + l * 8];
    #pragma unroll
    for (int cs = 0; cs < 4; ++cs)
        nv[cs] = *(const s16x8*)&vF[VB(b, cs, iq * 16) + l * 8];

    __syncthreads();   // rls ready (only barrier)

    for (int t = 0; t < 16; ++t) {
        s16x8 kA[2][2] = {{nk[0][0], nk[0][1]}, {nk[1][0], nk[1][1]}};
        s16x8 vA[4] = {nv[0], nv[1], nv[2], nv[3]};
        if (t < 15) {
            #pragma unroll
            for (int s = 0; s < 2; ++s)
                #pragma unroll
                for (int kc = 0; kc < 2; ++kc)
                    nk[s][kc] = *(const s16x8*)&kF[
                        FB(b, iq * 32 + (t + 1) * 2 + s, kc) + l * 8];
            #pragma unroll
            for (int cs = 0; cs < 4; ++cs)
                nv[cs] = *(const s16x8*)&vF[VB(b, cs, iq * 16 + t + 1) + l * 8];
        }

        f32x4 nl0 = *(const f32x4*)&rls[t * 32 + lq * 4];
        f32x4 nl1 = *(const f32x4*)&rls[t * 32 + 16 + lq * 4];

        // --- batched score MFMAs: 4 independent 2-deep chains ---
        f32x4 s0[2], s1[2];
        __builtin_amdgcn_s_setprio(1);
        #pragma unroll
        for (int js = 0; js < 2; ++js) {
            s0[js] = nl0; s1[js] = nl1;   // C-init = -log2(l[i]) per i-row
            s0[js] = __builtin_amdgcn_mfma_f32_16x16x32_bf16(kA[0][0], qb[js][0], s0[js], 0,0,0);
            s0[js] = __builtin_amdgcn_mfma_f32_16x16x32_bf16(kA[0][1], qb[js][1], s0[js], 0,0,0);
            s1[js] = __builtin_amdgcn_mfma_f32_16x16x32_bf16(kA[1][0], qb[js][0], s1[js], 0,0,0);
            s1[js] = __builtin_amdgcn_mfma_f32_16x16x32_bf16(kA[1][1], qb[js][1], s1[js], 0,0,0);
        }
        __builtin_amdgcn_s_setprio(0);

        // --- all exps/packs, then both wave-private LDS transposes ---
        #pragma unroll
        for (int js = 0; js < 2; ++js) {
            unsigned int P0[2], P1[2];
            P0[0] = pk_fast(hexp2(s0[js][0]), hexp2(s0[js][1]));
            P0[1] = pk_fast(hexp2(s0[js][2]), hexp2(s0[js][3]));
            P1[0] = pk_fast(hexp2(s1[js][0]), hexp2(s1[js][1]));
            P1[1] = pk_fast(hexp2(s1[js][2]), hexp2(s1[js][3]));
            *(uint2*)&wts[w][js][lm][4 * lq]      = make_uint2(P0[0], P0[1]);
            *(uint2*)&wts[w][js][lm][16 + 4 * lq] = make_uint2(P1[0], P1[1]);
        }
        s16x8 Bv0 = *(const s16x8*)&wts[w][0][lm][8 * lq];
        s16x8 Bv1 = *(const s16x8*)&wts[w][1][lm][8 * lq];

        __builtin_amdgcn_s_setprio(1);
        #pragma unroll
        for (int cs = 0; cs < 4; ++cs) {
            acc[0][cs] = __builtin_amdgcn_mfma_f32_16x16x32_bf16(vA[cs], Bv0, acc[0][cs], 0,0,0);
            acc[1][cs] = __builtin_amdgcn_mfma_f32_16x16x32_bf16(vA[cs], Bv1, acc[1][cs], 0,0,0);
        }
        __builtin_amdgcn_s_setprio(0);
    }

    unsigned short* Up = U + ((size_t)iq * NB + b) * NPOS * CH;
    #pragma unroll
    for (int js = 0; js < 2; ++js)
        #pragma unroll
        for (int cs = 0; cs < 4; ++cs) {
            uint2 st = make_uint2(pk_rne(acc[js][cs][0], acc[js][cs][1]),
                                  pk_rne(acc[js][cs][2], acc[js][cs][3]));
            *(uint2*)&Up[(size_t)(j0 + w * 32 + js * 16 + lm) * CH
                         + cs * 16 + lq * 4] = st;
        }
}

// ---------------------------------------------------------------------------
// Kernel 4: post projection + residual with cooperative U-sum.
// (round-5 proven, unchanged)
// ---------------------------------------------------------------------------
__global__ __launch_bounds__(256) void post_kernel(
    const float* __restrict__ x, const float* __restrict__ Wpost,
    const unsigned short* __restrict__ U, float* __restrict__ out)
{
    __shared__ __align__(16) unsigned short BfL[32][68];  // 4.25 KB (pad->68)
    const int b  = blockIdx.y;
    const int p0 = blockIdx.x * 32;
    const int tid = threadIdx.x;
    const size_t PS = (size_t)NB * NPOS * CH;

    // cooperative U-sum: thread = (pos p = tid>>3, channel-group cg = tid&7)
    {
        const int p  = tid >> 3;          // 0..31
        const int cg = tid & 7;           // 0..7 -> channels cg*8..cg*8+7
        const unsigned short* u = U + ((size_t)b * NPOS + p0 + p) * CH + cg * 8;
        float sv[8] = {};
        #pragma unroll
        for (int qq = 0; qq < 8; ++qq) {
            union { s16x8 v; unsigned short us[8]; } uu;
            uu.v = *(const s16x8*)(u + (size_t)qq * PS);
            #pragma unroll
            for (int j = 0; j < 8; ++j) sv[j] += bf2f(uu.us[j]);
        }
        *(uint2*)&BfL[p][cg * 8]     = make_uint2(pk_rne(sv[0], sv[1]),
                                                  pk_rne(sv[2], sv[3]));
        *(uint2*)&BfL[p][cg * 8 + 4] = make_uint2(pk_rne(sv[4], sv[5]),
                                                  pk_rne(sv[6], sv[7]));
    }
    __syncthreads();

    const int w = tid >> 6, l = tid & 63, lm = l & 15, lq = l >> 4;
    const int psub = (w & 1) * 16, ohalf = w >> 1;
    const int p = p0 + psub + lm;

    s16x8 Bf[2];
    #pragma unroll
    for (int ck = 0; ck < 2; ++ck) {
        uint2 lo = *(const uint2*)&BfL[psub + lm][ck * 32 + lq * 8];
        uint2 hi = *(const uint2*)&BfL[psub + lm][ck * 32 + lq * 8 + 4];
        union { unsigned int u[4]; s16x8 v; } cb;
        cb.u[0] = lo.x; cb.u[1] = lo.y; cb.u[2] = hi.x; cb.u[3] = hi.y;
        Bf[ck] = cb.v;
    }

    #pragma unroll
    for (int ot = 0; ot < 4; ++ot) {
        const int o0 = (ohalf * 4 + ot) * 16;
        f32x4 acc = {0.f, 0.f, 0.f, 0.f};
        #pragma unroll
        for (int ck = 0; ck < 2; ++ck) {
            const float* wp = Wpost + (o0 + lm) * CH + ck * 32 + lq * 8;
            union { unsigned int u[4]; s16x8 v; } ca;
            #pragma unroll
            for (int j = 0; j < 4; ++j) ca.u[j] = pk_rne(wp[2*j], wp[2*j+1]);
            acc = __builtin_amdgcn_mfma_f32_16x16x32_bf16(ca.v, Bf[ck], acc, 0,0,0);
        }
        #pragma unroll
        for (int r = 0; r < 4; ++r) {
            size_t gi = ((size_t)b * CIN + o0 + lq * 4 + r) * NPOS + p;
            out[gi] = x[gi] + acc[r];
        }
    }
}

extern "C" void kernel_launch(void* const* d_in, const int* in_sizes, int n_in,
                              void* d_out, int out_size, void* d_ws, size_t ws_size,
                              hipStream_t stream) {
    const float* x     = (const float*)d_in[0];
    const float* Wq    = (const float*)d_in[1];
    const float* Wk    = (const float*)d_in[2];
    const float* Wv    = (const float*)d_in[3];
    const float* Wpost = (const float*)d_in[4];
    float* out = (float*)d_out;

    // ws: kF(1MB) qF(1MB) vF(1MB) lpart(512KB) U(8MB bf16, 8 partials)
    unsigned short* kF = (unsigned short*)d_ws;
    unsigned short* qF = kF + (size_t)NB * NPOS * CH;
    unsigned short* vF = qF + (size_t)NB * NPOS * CH;
    float* lpart = (float*)(vF + (size_t)NB * NPOS * CH);
    unsigned short* U = (unsigned short*)(lpart + (size_t)JQ * NB * NPOS);

    qkv_kernel  <<<dim3(NPOS / 16, NB),     256, 0, stream>>>(x, Wq, Wk, Wv, kF, qF, vF);
    stats_kernel<<<dim3(32, JQ, NB),        256, 0, stream>>>(kF, qF, lpart);
    agg_kernel  <<<dim3(NPOS / 128, 8, NB), 256, 0, stream>>>(kF, qF, vF, lpart, U);
    post_kernel <<<dim3(NPOS / 32, NB),     256, 0, stream>>>(x, Wpost, U, out);
}